// Round 1
// baseline (486.871 us; speedup 1.0000x reference)
//
#include <hip/hip_runtime.h>
#include <hip/hip_bf16.h>
#include <stdint.h>

typedef __bf16 bf16_t;
typedef __bf16 bf16x8 __attribute__((ext_vector_type(8)));
typedef float  f32x4  __attribute__((ext_vector_type(4)));

#define BM 128
#define BN 128
#define BK 64

// ---------------- Kernel 1: global absmax of weight ----------------
__global__ void k_absmax(const float* __restrict__ w, unsigned int* __restrict__ out_bits, int n4) {
    int i = blockIdx.x * blockDim.x + threadIdx.x;
    int stride = gridDim.x * blockDim.x;
    const float4* w4 = (const float4*)w;
    float m = 0.0f;
    for (; i < n4; i += stride) {
        float4 v = w4[i];
        m = fmaxf(m, fmaxf(fmaxf(fabsf(v.x), fabsf(v.y)), fmaxf(fabsf(v.z), fabsf(v.w))));
    }
    #pragma unroll
    for (int off = 32; off; off >>= 1)
        m = fmaxf(m, __shfl_xor(m, off));
    if ((threadIdx.x & 63) == 0)
        atomicMax(out_bits, __float_as_uint(m));  // all values >= 0: uint order == float order
}

// ---------------- e4m3fn round-to-nearest-even (positive inputs, <= 448) ----------------
__device__ __forceinline__ float e4m3_rne(float v) {
    if (v < 0.015625f) {                 // subnormal range: quantum 2^-9
        return rintf(v * 512.0f) * (1.0f / 512.0f);
    }
    unsigned int u = __float_as_uint(v);
    unsigned int keep = u >> 20;         // sign+exp+3 mantissa bits
    unsigned int r = u & 0xFFFFFu;       // 20 dropped bits
    if (r > 0x80000u || (r == 0x80000u && (keep & 1u))) keep++;
    return __uint_as_float(keep << 20);
}

// ---------------- Kernel 2: NVFP4 fake-quantize weight -> bf16 ----------------
__global__ void k_quantize(const float* __restrict__ w, bf16_t* __restrict__ wq,
                           const unsigned int* __restrict__ maxbits, int nblk) {
    int t = blockIdx.x * blockDim.x + threadIdx.x;
    if (t >= nblk) return;
    float gmax = __uint_as_float(*maxbits);
    float gs = 2688.0f / gmax;                      // (6*448)/max|w|, fp32
    const float4* w4 = (const float4*)w + (size_t)t * 4;
    float4 v0 = w4[0], v1 = w4[1], v2 = w4[2], v3 = w4[3];
    float vv[16];
    vv[0]=v0.x; vv[1]=v0.y; vv[2]=v0.z; vv[3]=v0.w;
    vv[4]=v1.x; vv[5]=v1.y; vv[6]=v1.z; vv[7]=v1.w;
    vv[8]=v2.x; vv[9]=v2.y; vv[10]=v2.z; vv[11]=v2.w;
    vv[12]=v3.x; vv[13]=v3.y; vv[14]=v3.z; vv[15]=v3.w;
    float bmax = 0.0f;
    #pragma unroll
    for (int j = 0; j < 16; ++j) bmax = fmaxf(bmax, fabsf(vv[j]));
    float s_decb = bmax / 6.0f;
    float xs_in  = fminf(s_decb * gs, 448.0f);      // clip (always >= 0)
    float xs_f   = e4m3_rne(xs_in);
    float s_encb = gs / fmaxf(xs_f, 1e-12f);
    float dscale = xs_f / gs;
    bf16x8 o0, o1;
    #pragma unroll
    for (int j = 0; j < 16; ++j) {
        float xsc = vv[j] * s_encb;
        float a = fabsf(xsc);
        // exact reference threshold chain: alternating <= and <
        float mag = (a <= 0.25f) ? 0.0f
                  : (a <  0.75f) ? 0.5f
                  : (a <= 1.25f) ? 1.0f
                  : (a <  1.75f) ? 1.5f
                  : (a <= 2.5f ) ? 2.0f
                  : (a <  3.5f ) ? 3.0f
                  : (a <= 5.0f ) ? 4.0f : 6.0f;
        float sgn = __builtin_copysignf(1.0f, xsc);
        float val = (sgn * mag) * dscale;
        if (j < 8) o0[j] = (bf16_t)val; else o1[j - 8] = (bf16_t)val;
    }
    *(bf16x8*)(wq + (size_t)t * 16)     = o0;
    *(bf16x8*)(wq + (size_t)t * 16 + 8) = o1;
}

// ---------------- Kernel 3: x fp32 -> bf16 ----------------
__global__ void k_cvt_x(const float* __restrict__ x, bf16_t* __restrict__ xb, long n8) {
    long i = blockIdx.x * (long)blockDim.x + threadIdx.x;
    long stride = (long)gridDim.x * blockDim.x;
    const float4* x4 = (const float4*)x;
    for (; i < n8; i += stride) {
        float4 a = x4[2 * i], b = x4[2 * i + 1];
        bf16x8 o;
        o[0] = (bf16_t)a.x; o[1] = (bf16_t)a.y; o[2] = (bf16_t)a.z; o[3] = (bf16_t)a.w;
        o[4] = (bf16_t)b.x; o[5] = (bf16_t)b.y; o[6] = (bf16_t)b.z; o[7] = (bf16_t)b.w;
        *(bf16x8*)(xb + i * 8) = o;
    }
}

// ---------------- global -> LDS 16B async ----------------
__device__ __forceinline__ void gload16(const bf16_t* g, bf16_t* l) {
    __builtin_amdgcn_global_load_lds(
        (const __attribute__((address_space(1))) unsigned int*)g,
        (__attribute__((address_space(3))) unsigned int*)l,
        16, 0, 0);
}

// ---------------- Kernel 4: bf16 GEMM  C[M][N] = A[M][K] * Bt[N][K]^T + bias ----------------
__global__ __launch_bounds__(256) void k_gemm(
        const bf16_t* __restrict__ A,   // [M][K]
        const bf16_t* __restrict__ Bt,  // [N][K]
        const float*  __restrict__ bias,
        float* __restrict__ C, int M, int N, int K) {
    __shared__ bf16_t As[BM * BK];
    __shared__ bf16_t Bs[BN * BK];

    // XCD-aware bijective swizzle (gridDim.x % 8 == 0 here)
    int bid = blockIdx.x;
    int cpx = gridDim.x >> 3;
    int swz = (bid & 7) * cpx + (bid >> 3);
    int nbn = N / BN;
    int bm = swz / nbn, bn = swz % nbn;
    int m0 = bm * BM, n0 = bn * BN;

    int tid  = threadIdx.x;
    int lane = tid & 63;
    int w    = tid >> 6;        // wave 0..3
    int wr   = w >> 1, wc = w & 1;

    f32x4 acc[4][4] = {};

    // staging: thread t covers row = t/8 (of 32), 16B chunk = t%8; 4 rounds of 32 rows
    int srow   = tid >> 3;
    int schunk = tid & 7;
    const bf16_t* Ap = A  + (size_t)(m0 + srow) * K + schunk * 8;
    const bf16_t* Bp = Bt + (size_t)(n0 + srow) * K + schunk * 8;
    bf16_t* Asd = As + tid * 8;
    bf16_t* Bsd = Bs + tid * 8;

    int fr = lane & 15;          // fragment row (m or n)
    int fk = (lane >> 4) * 8;    // fragment k offset within 32

    for (int kt = 0; kt < K; kt += BK) {
        __syncthreads();
        #pragma unroll
        for (int r = 0; r < 4; ++r) {
            gload16(Ap + kt + (size_t)r * 32 * K, Asd + r * 32 * BK);
            gload16(Bp + kt + (size_t)r * 32 * K, Bsd + r * 32 * BK);
        }
        __syncthreads();
        #pragma unroll
        for (int kk = 0; kk < BK; kk += 32) {
            bf16x8 af[4], bfr[4];
            #pragma unroll
            for (int i = 0; i < 4; ++i)
                af[i] = *(const bf16x8*)&As[(wr * 64 + i * 16 + fr) * BK + kk + fk];
            #pragma unroll
            for (int j = 0; j < 4; ++j)
                bfr[j] = *(const bf16x8*)&Bs[(wc * 64 + j * 16 + fr) * BK + kk + fk];
            #pragma unroll
            for (int i = 0; i < 4; ++i) {
                #pragma unroll
                for (int j = 0; j < 4; ++j)
                    acc[i][j] = __builtin_amdgcn_mfma_f32_16x16x32_bf16(af[i], bfr[j], acc[i][j], 0, 0, 0);
            }
        }
    }

    // epilogue: C/D mapping col = lane&15, row = (lane>>4)*4 + reg  (m89-verified)
    int crow = (lane >> 4) * 4;
    int ccol = lane & 15;
    float bv[4];
    #pragma unroll
    for (int j = 0; j < 4; ++j) bv[j] = bias[n0 + wc * 64 + j * 16 + ccol];
    #pragma unroll
    for (int i = 0; i < 4; ++i) {
        size_t mrow = (size_t)(m0 + wr * 64 + i * 16 + crow);
        #pragma unroll
        for (int j = 0; j < 4; ++j) {
            float* cp = C + mrow * N + (n0 + wc * 64 + j * 16 + ccol);
            #pragma unroll
            for (int r = 0; r < 4; ++r)
                cp[(size_t)r * N] = acc[i][j][r] + bv[j];
        }
    }
}

extern "C" void kernel_launch(void* const* d_in, const int* in_sizes, int n_in,
                              void* d_out, int out_size, void* d_ws, size_t ws_size,
                              hipStream_t stream) {
    const float* x    = (const float*)d_in[0];
    const float* wgt  = (const float*)d_in[1];
    const float* bias = (const float*)d_in[2];
    float* out = (float*)d_out;

    const int N = in_sizes[2];            // 4096 (OUT)
    const int K = in_sizes[1] / N;        // 4096 (IN)
    const int M = in_sizes[0] / K;        // 8192 (B*S)

    // workspace layout: [0,256): absmax bits; then wq bf16 (N*K); then xb bf16 (M*K)
    unsigned int* maxbits = (unsigned int*)d_ws;
    bf16_t* wq = (bf16_t*)((char*)d_ws + 256);
    bf16_t* xb = (bf16_t*)((char*)d_ws + 256 + (size_t)N * K * sizeof(bf16_t));

    hipMemsetAsync(d_ws, 0, 256, stream);
    k_absmax<<<512, 256, 0, stream>>>(wgt, maxbits, N * K / 4);
    int nblk = N * K / 16;
    k_quantize<<<(nblk + 255) / 256, 256, 0, stream>>>(wgt, wq, maxbits, nblk);
    long n8 = (long)M * K / 8;
    k_cvt_x<<<2048, 256, 0, stream>>>(x, xb, n8);
    dim3 grid((M / BM) * (N / BN));
    k_gemm<<<grid, 256, 0, stream>>>(xb, wq, bias, out, M, N, K);
}

// Round 2
// 348.460 us; speedup vs baseline: 1.3972x; 1.3972x over previous
//
#include <hip/hip_runtime.h>
#include <hip/hip_bf16.h>
#include <stdint.h>

typedef __bf16 bf16_t;
typedef __bf16 bf16x8 __attribute__((ext_vector_type(8)));
typedef float  f32x4  __attribute__((ext_vector_type(4)));

#define BM 256
#define BN 256
#define BK 64
#define NTHREADS 512

// ---------------- Kernel 1: global absmax of weight ----------------
__global__ void k_absmax(const float* __restrict__ w, unsigned int* __restrict__ out_bits, int n4) {
    int i = blockIdx.x * blockDim.x + threadIdx.x;
    int stride = gridDim.x * blockDim.x;
    const float4* w4 = (const float4*)w;
    float m = 0.0f;
    for (; i < n4; i += stride) {
        float4 v = w4[i];
        m = fmaxf(m, fmaxf(fmaxf(fabsf(v.x), fabsf(v.y)), fmaxf(fabsf(v.z), fabsf(v.w))));
    }
    #pragma unroll
    for (int off = 32; off; off >>= 1)
        m = fmaxf(m, __shfl_xor(m, off));
    if ((threadIdx.x & 63) == 0)
        atomicMax(out_bits, __float_as_uint(m));  // values >= 0: uint order == float order
}

// ---------------- e4m3fn round-to-nearest-even (positive inputs, <= 448) ----------------
__device__ __forceinline__ float e4m3_rne(float v) {
    if (v < 0.015625f) {                 // subnormal range: quantum 2^-9
        return rintf(v * 512.0f) * (1.0f / 512.0f);
    }
    unsigned int u = __float_as_uint(v);
    unsigned int keep = u >> 20;         // sign+exp+3 mantissa bits
    unsigned int r = u & 0xFFFFFu;       // 20 dropped bits
    if (r > 0x80000u || (r == 0x80000u && (keep & 1u))) keep++;
    return __uint_as_float(keep << 20);
}

// ---------------- Kernel 2: NVFP4 fake-quantize weight -> bf16 ----------------
__global__ void k_quantize(const float* __restrict__ w, bf16_t* __restrict__ wq,
                           const unsigned int* __restrict__ maxbits, int nblk) {
    int t = blockIdx.x * blockDim.x + threadIdx.x;
    if (t >= nblk) return;
    float gmax = __uint_as_float(*maxbits);
    float gs = 2688.0f / gmax;                      // (6*448)/max|w|, fp32
    const float4* w4 = (const float4*)w + (size_t)t * 4;
    float4 v0 = w4[0], v1 = w4[1], v2 = w4[2], v3 = w4[3];
    float vv[16];
    vv[0]=v0.x; vv[1]=v0.y; vv[2]=v0.z; vv[3]=v0.w;
    vv[4]=v1.x; vv[5]=v1.y; vv[6]=v1.z; vv[7]=v1.w;
    vv[8]=v2.x; vv[9]=v2.y; vv[10]=v2.z; vv[11]=v2.w;
    vv[12]=v3.x; vv[13]=v3.y; vv[14]=v3.z; vv[15]=v3.w;
    float bmax = 0.0f;
    #pragma unroll
    for (int j = 0; j < 16; ++j) bmax = fmaxf(bmax, fabsf(vv[j]));
    float s_decb = bmax / 6.0f;
    float xs_in  = fminf(s_decb * gs, 448.0f);      // clip (always >= 0)
    float xs_f   = e4m3_rne(xs_in);
    float s_encb = gs / fmaxf(xs_f, 1e-12f);
    float dscale = xs_f / gs;
    bf16x8 o0, o1;
    #pragma unroll
    for (int j = 0; j < 16; ++j) {
        float xsc = vv[j] * s_encb;
        float a = fabsf(xsc);
        float mag = (a <= 0.25f) ? 0.0f
                  : (a <  0.75f) ? 0.5f
                  : (a <= 1.25f) ? 1.0f
                  : (a <  1.75f) ? 1.5f
                  : (a <= 2.5f ) ? 2.0f
                  : (a <  3.5f ) ? 3.0f
                  : (a <= 5.0f ) ? 4.0f : 6.0f;
        float sgn = __builtin_copysignf(1.0f, xsc);
        float val = (sgn * mag) * dscale;
        if (j < 8) o0[j] = (bf16_t)val; else o1[j - 8] = (bf16_t)val;
    }
    *(bf16x8*)(wq + (size_t)t * 16)     = o0;
    *(bf16x8*)(wq + (size_t)t * 16 + 8) = o1;
}

// ---------------- Kernel 3: x fp32 -> bf16 ----------------
__global__ void k_cvt_x(const float* __restrict__ x, bf16_t* __restrict__ xb, long n8) {
    long i = blockIdx.x * (long)blockDim.x + threadIdx.x;
    long stride = (long)gridDim.x * blockDim.x;
    const float4* x4 = (const float4*)x;
    for (; i < n8; i += stride) {
        float4 a = x4[2 * i], b = x4[2 * i + 1];
        bf16x8 o;
        o[0] = (bf16_t)a.x; o[1] = (bf16_t)a.y; o[2] = (bf16_t)a.z; o[3] = (bf16_t)a.w;
        o[4] = (bf16_t)b.x; o[5] = (bf16_t)b.y; o[6] = (bf16_t)b.z; o[7] = (bf16_t)b.w;
        *(bf16x8*)(xb + i * 8) = o;
    }
}

// ---------------- helpers ----------------
__device__ __forceinline__ void BARRIER() {
    asm volatile("" ::: "memory");
    __builtin_amdgcn_s_barrier();
    asm volatile("" ::: "memory");
}

__device__ __forceinline__ void gload16(const bf16_t* g, bf16_t* l) {
    __builtin_amdgcn_global_load_lds(
        (const __attribute__((address_space(1))) unsigned int*)g,
        (__attribute__((address_space(3))) unsigned int*)l,
        16, 0, 0);
}

// swizzled fragment read: logical (row, granule g) -> physical granule row*8 + (g ^ (row&7))
__device__ __forceinline__ bf16x8 ldsf(const bf16_t* tile, int row, int g) {
    return *(const bf16x8*)(tile + (((row << 3) + (g ^ (row & 7))) << 3));
}

// ---------------- Kernel 4: 256x256 8-phase bf16 GEMM, C = A * Bt^T + bias ----------------
__global__ __launch_bounds__(NTHREADS, 2) void k_gemm(
        const bf16_t* __restrict__ A,   // [M][K]
        const bf16_t* __restrict__ Bt,  // [N][K]
        const float*  __restrict__ bias,
        float* __restrict__ C, int M, int N, int K) {
    __shared__ __align__(16) bf16_t sA[2][BM * BK];
    __shared__ __align__(16) bf16_t sB[2][BN * BK];

    // XCD-aware bijective swizzle (gridDim.x % 8 == 0 here)
    int bid = blockIdx.x;
    int cpx = gridDim.x >> 3;
    int swz = (bid & 7) * cpx + (bid >> 3);
    int nbn = N / BN;
    int m0 = (swz / nbn) * BM, n0 = (swz % nbn) * BN;

    int tid  = threadIdx.x;
    int lane = tid & 63;
    int w    = tid >> 6;         // 8 waves: 2 (M) x 4 (N)
    int wr   = w >> 2, wc = w & 3;
    int fr   = lane & 15;        // fragment row within 16
    int gk   = lane >> 4;        // k-granule 0..3

    // staging precompute: thread covers physical granules pf = H*1024 + r*512 + tid
    // inverse swizzle on the GLOBAL source; LDS dest stays linear (rule #21)
    int eoff[2][2], loff[2][2];
    #pragma unroll
    for (int H = 0; H < 2; ++H) {
        #pragma unroll
        for (int r = 0; r < 2; ++r) {
            int pf  = H * 1024 + r * 512 + tid;
            int row = pf >> 3;
            int lg  = (pf & 7) ^ (row & 7);
            eoff[H][r] = row * K + lg * 8;   // elements
            loff[H][r] = pf * 8;             // elements within tile
        }
    }
    const bf16_t* Ab = A  + (size_t)m0 * K;
    const bf16_t* Bb = Bt + (size_t)n0 * K;

#define STAGE(MAT, H, BUF, KK) do {                                          \
        gload16(MAT##b + eoff[H][0] + (KK), &s##MAT[BUF][loff[H][0]]);       \
        gload16(MAT##b + eoff[H][1] + (KK), &s##MAT[BUF][loff[H][1]]);       \
    } while (0)

    f32x4 acc[8][4] = {};

    // prologue: B(0), A(0), B(1) -> 12 loads; vmcnt(4) leaves B(1) in flight
    STAGE(B, 0, 0, 0);  STAGE(B, 1, 0, 0);
    STAGE(A, 0, 0, 0);  STAGE(A, 1, 0, 0);
    STAGE(B, 0, 1, BK); STAGE(B, 1, 1, BK);
    asm volatile("s_waitcnt vmcnt(4)" ::: "memory");
    BARRIER();

    const int NT = K / BK;
    const int rA = wr * 128 + fr;
    const int rB = wc * 64 + fr;

#define PHASE(QM, STAGE_STMT, TAIL_STMT)                                                              \
    {                                                                                                  \
        bf16x8 a00 = ldsf(pA, rA + (QM)*32,      gk);                                                  \
        bf16x8 a01 = ldsf(pA, rA + (QM)*32,      4 + gk);                                              \
        bf16x8 a10 = ldsf(pA, rA + (QM)*32 + 16, gk);                                                  \
        bf16x8 a11 = ldsf(pA, rA + (QM)*32 + 16, 4 + gk);                                              \
        STAGE_STMT;                                                                                    \
        BARRIER();                                                                                     \
        asm volatile("s_waitcnt lgkmcnt(0)" ::: "memory");                                             \
        __builtin_amdgcn_s_setprio(1);                                                                 \
        _Pragma("unroll")                                                                              \
        for (int j = 0; j < 4; ++j) {                                                                  \
            acc[(QM)*2+0][j] = __builtin_amdgcn_mfma_f32_16x16x32_bf16(a00, bfr[j][0], acc[(QM)*2+0][j], 0, 0, 0); \
            acc[(QM)*2+0][j] = __builtin_amdgcn_mfma_f32_16x16x32_bf16(a01, bfr[j][1], acc[(QM)*2+0][j], 0, 0, 0); \
            acc[(QM)*2+1][j] = __builtin_amdgcn_mfma_f32_16x16x32_bf16(a10, bfr[j][0], acc[(QM)*2+1][j], 0, 0, 0); \
            acc[(QM)*2+1][j] = __builtin_amdgcn_mfma_f32_16x16x32_bf16(a11, bfr[j][1], acc[(QM)*2+1][j], 0, 0, 0); \
        }                                                                                              \
        __builtin_amdgcn_s_setprio(0);                                                                 \
        TAIL_STMT;                                                                                     \
        BARRIER();                                                                                     \
    }

    for (int t = 0; t < NT; ++t) {
        int cur = t & 1;
        const bf16_t* pA = sA[cur];
        const bf16_t* pB = sB[cur];
        int ktA = ((t + 1 < NT) ? t + 1 : NT - 1) * BK;   // A staged 1 tile ahead -> buf cur^1
        int ktB = ((t + 2 < NT) ? t + 2 : NT - 1) * BK;   // B staged 2 tiles ahead -> buf cur
        int bA = cur ^ 1, bB = cur;

        // B-fragments for the whole K-tile (read once, reused across 4 phases)
        bf16x8 bfr[4][2];
        #pragma unroll
        for (int j = 0; j < 4; ++j) {
            bfr[j][0] = ldsf(pB, rB + j * 16, gk);
            bfr[j][1] = ldsf(pB, rB + j * 16, 4 + gk);
        }

        PHASE(0, STAGE(A, 0, bA, ktA), (void)0);
        PHASE(1, STAGE(A, 1, bA, ktA), (void)0);
        PHASE(2, STAGE(B, 0, bB, ktB), (void)0);
        PHASE(3, STAGE(B, 1, bB, ktB),
              asm volatile("s_waitcnt vmcnt(4)" ::: "memory"));
    }
    asm volatile("s_waitcnt vmcnt(0)" ::: "memory");  // drain tail garbage stages before endpgm

    // epilogue: C/D mapping col = lane&15, row = (lane>>4)*4 + reg
    int crow = (lane >> 4) * 4;
    int ccol = lane & 15;
    float bv[4];
    #pragma unroll
    for (int j = 0; j < 4; ++j) bv[j] = bias[n0 + wc * 64 + j * 16 + ccol];
    #pragma unroll
    for (int i = 0; i < 8; ++i) {
        size_t mrow = (size_t)(m0 + wr * 128 + i * 16 + crow);
        #pragma unroll
        for (int j = 0; j < 4; ++j) {
            float* cp = C + mrow * N + (n0 + wc * 64 + j * 16 + ccol);
            #pragma unroll
            for (int r = 0; r < 4; ++r)
                cp[(size_t)r * N] = acc[i][j][r] + bv[j];
        }
    }
#undef PHASE
#undef STAGE
}

extern "C" void kernel_launch(void* const* d_in, const int* in_sizes, int n_in,
                              void* d_out, int out_size, void* d_ws, size_t ws_size,
                              hipStream_t stream) {
    const float* x    = (const float*)d_in[0];
    const float* wgt  = (const float*)d_in[1];
    const float* bias = (const float*)d_in[2];
    float* out = (float*)d_out;

    const int N = in_sizes[2];            // 4096 (OUT)
    const int K = in_sizes[1] / N;        // 4096 (IN)
    const int M = in_sizes[0] / K;        // 8192 (B*S)

    unsigned int* maxbits = (unsigned int*)d_ws;
    bf16_t* wq = (bf16_t*)((char*)d_ws + 256);
    bf16_t* xb = (bf16_t*)((char*)d_ws + 256 + (size_t)N * K * sizeof(bf16_t));

    hipMemsetAsync(d_ws, 0, 256, stream);
    k_absmax<<<512, 256, 0, stream>>>(wgt, maxbits, N * K / 4);
    int nblk = N * K / 16;
    k_quantize<<<(nblk + 255) / 256, 256, 0, stream>>>(wgt, wq, maxbits, nblk);
    long n8 = (long)M * K / 8;
    k_cvt_x<<<2048, 256, 0, stream>>>(x, xb, n8);
    dim3 grid((M / BM) * (N / BN));
    k_gemm<<<grid, NTHREADS, 0, stream>>>(xb, wq, bias, out, M, N, K);
}